// Round 5
// baseline (305.084 us; speedup 1.0000x reference)
//
#include <hip/hip_runtime.h>
#include <stdint.h>

typedef unsigned short u16;
typedef unsigned int u32;
typedef short bf8_t __attribute__((ext_vector_type(8)));   // 8 bf16 = 4 VGPR
typedef float f4_t  __attribute__((ext_vector_type(4)));
typedef float f16_t __attribute__((ext_vector_type(16)));  // 32x32 MFMA C/D

#define LOG2E 1.44269504088896340736f

// packed f32x2 -> bf16x2 (RNE), single instruction
static __device__ __forceinline__ u32 pkbf(float lo, float hi){
  u32 r; asm("v_cvt_pk_bf16_f32 %0, %1, %2" : "=v"(r) : "v"(lo), "v"(hi)); return r;
}

// Convert one 32x32 C'-tile (lane = n-col l31, regs = m per C-layout
// m=(r&3)+8*(r>>2)+4*l5) into two A/B frags with frag-k = m:
// f0 covers m=0..15, f1 covers m=16..31. Output frag lane l, u32[i] holds
// m = 8*l5 + 2i, 2i+1 (f0) / 16 + that (f1). Own half provides pk pairs;
// the other 8 m's live at lane^32 -> one shfl_xor(32) per pair-slot.
static __device__ __forceinline__ void cvt_tile(const f16_t c, bool hi5, bf8_t& f0, bf8_t& f1){
  u32 p0 = pkbf(c[0], c[1]),  p1 = pkbf(c[2], c[3]);
  u32 p2 = pkbf(c[4], c[5]),  p3 = pkbf(c[6], c[7]);
  u32 p4 = pkbf(c[8], c[9]),  p5 = pkbf(c[10], c[11]);
  u32 p6 = pkbf(c[12], c[13]), p7 = pkbf(c[14], c[15]);
  u32 t0 = hi5 ? p0 : p2,  t1 = hi5 ? p1 : p3;
  u32 t2 = hi5 ? p4 : p6,  t3 = hi5 ? p5 : p7;
  u32 s0 = (u32)__shfl_xor((int)t0, 32);
  u32 s1 = (u32)__shfl_xor((int)t1, 32);
  u32 s2 = (u32)__shfl_xor((int)t2, 32);
  u32 s3 = (u32)__shfl_xor((int)t3, 32);
  union { u32 u[4]; bf8_t b; } x0, x1;
  x0.u[0] = hi5 ? s0 : p0;  x0.u[1] = hi5 ? s1 : p1;
  x0.u[2] = hi5 ? p2 : s0;  x0.u[3] = hi5 ? p3 : s1;
  x1.u[0] = hi5 ? s2 : p4;  x1.u[1] = hi5 ? s3 : p5;
  x1.u[2] = hi5 ? p6 : s2;  x1.u[3] = hi5 ? p7 : s3;
  f0 = x0.b; f1 = x1.b;
}

#define MFMA32(a, b, c) __builtin_amdgcn_mfma_f32_32x32x16_bf16(a, b, c, 0, 0, 0)

// ---------------- pre-kernels ----------------

__global__ void wconv_kernel(const float* __restrict__ qkvw, const float* __restrict__ projw,
                             u16* __restrict__ wq, u16* __restrict__ wp){
  int i4 = blockIdx.x * blockDim.x + threadIdx.x;
  const float* src; u16* dst; int off;
  if (i4 < 49152){ src = qkvw; dst = wq; off = i4 * 4; }
  else           { src = projw; dst = wp; off = (i4 - 49152) * 4; }
  float4 v = *reinterpret_cast<const float4*>(src + off);
  uint2 p; p.x = pkbf(v.x, v.y); p.y = pkbf(v.z, v.w);
  *reinterpret_cast<uint2*>(dst + off) = p;
}

__global__ void cpbmlp_kernel(const float* __restrict__ tab, const float* __restrict__ w1,
                              const float* __restrict__ b1, const float* __restrict__ w2,
                              float* __restrict__ tbl){
  int u = blockIdx.x * blockDim.x + threadIdx.x;
  if (u >= 225 * 8) return;
  int i = u >> 3, h = u & 7;
  float c0 = tab[2*i], c1 = tab[2*i+1];
  const float* w2h = w2 + h * 512;
  float acc = 0.f;
  for (int j = 0; j < 512; j++){
    float hv = fmaf(c1, w1[2*j+1], fmaf(c0, w1[2*j], b1[j]));
    hv = fmaxf(hv, 0.f);
    acc = fmaf(hv, w2h[j], acc);
  }
  tbl[i*8 + h] = acc;
}

// bias for S^T = K.Q^T C-layout: biasF[(((h*4 + kt*2 + qt)*4 + r4)*64 + lane)*4 + rl]
//   = 16*sigmoid(cpb[h, query, key]) * log2e
// query = 32*qt + (lane&31); key = 32*kt + rl + 8*r4 + 4*(lane>>5)
__global__ void cpbgather_kernel(const float* __restrict__ tbl, const int* __restrict__ idx,
                                 const float* __restrict__ scale, float* __restrict__ biasF,
                                 float* __restrict__ scf){
  int u = blockIdx.x * blockDim.x + threadIdx.x;   // 0..32767
  int rl   = u & 3;
  int lane = (u >> 2) & 63;
  int r4   = (u >> 8) & 3;
  int tile = (u >> 10) & 3;       // kt*2 + qt
  int hh   = (u >> 12) & 7;
  int qt = tile & 1, kt = tile >> 1;
  int query = 32*qt + (lane & 31);
  int key   = 32*kt + rl + 8*r4 + 4*(lane >> 5);
  int id = idx[query*64 + key];
  float xv = tbl[id*8 + hh];
  float s = 1.f / (1.f + expf(-xv));
  biasF[u] = 16.f * s * LOG2E;
  if (u < 8){
    float sc = fminf(scale[u], 4.6051701859880913680f);  // log(100)
    scf[u] = expf(sc) * LOG2E;
  }
}

// ---------------- main fused kernel ----------------
// Persistent: 512 blocks (2/CU), each handles 4 consecutive windows.
// 8 waves, wave w = head w end-to-end, 32x32x16 MFMAs, in-register cvt_tile.
// x tile for window i+1 prefetched (global->reg) during proj of window i (T14).
#define XS 264    // x / O tile stride in u16 (256+8); 528 B
#define NWIN 4

__global__ __launch_bounds__(512, 4)
void winattn_kernel(const float* __restrict__ x, const u16* __restrict__ wq,
                    const u16* __restrict__ wp, const float* __restrict__ qb,
                    const float* __restrict__ vbias, const float* __restrict__ biasF,
                    const float* __restrict__ scf, const float* __restrict__ projb,
                    float* __restrict__ out){
  __shared__ u16 xlds[64 * XS];   // x bf16 (rewritten each window by prefetch)
  __shared__ u16 olds[64 * XS];   // attention output bf16

  const int b0 = blockIdx.x * NWIN;
  const int t = threadIdx.x;
  const int w = t >> 6, lane = t & 63;
  const int l31 = lane & 31, l5 = lane >> 5;
  const bool hi5 = (l5 != 0);
  const int h = w;

  // ---- prologue: stage x[b0] -> LDS bf16 (only exposed stage) ----
  {
    const float* xg = x + (size_t)b0 * 16384;
    #pragma unroll
    for (int i = 0; i < 8; i++){
      int fi = t + 512 * i;
      float4 v = *reinterpret_cast<const float4*>(xg + fi * 4);
      uint2 p; p.x = pkbf(v.x, v.y); p.y = pkbf(v.z, v.w);
      int row = fi >> 6, c = (fi & 63) * 4;
      *reinterpret_cast<uint2*>(&xlds[row * XS + c]) = p;
    }
  }
  __syncthreads();

  #pragma unroll 1
  for (int it = 0; it < NWIN; ++it){
    const int b = b0 + it;

    bf8_t qf00, qf01, qf10, qf11;   // q B-frags [token-tile][k-block over d]
    bf8_t kf00, kf01, kf10, kf11;   // k A-frags
    bf8_t vf0, vf1, vf2, vf3;       // v A-frags [key-block]

    // ---- phase A: q,k transposed GEMM (A = W rows, B = x tokens) ----
    {
      f16_t cq0, cq1, ck0, ck1;     // C'[d][token], token tiles 0/1
      #pragma unroll
      for (int r = 0; r < 16; r++){
        float bqr = qb[32*h + (r & 3) + 8*(r >> 2) + 4*l5];
        cq0[r] = bqr; cq1[r] = bqr; ck0[r] = 0.f; ck1[r] = 0.f;
      }
      const u16* wqr = wq + (size_t)(32*h + l31) * 256;
      const u16* wkr = wqr + 256 * 256;
      #pragma unroll 4
      for (int ks = 0; ks < 16; ks++){
        const int ko = ks * 16 + 8 * l5;
        bf8_t aq  = *reinterpret_cast<const bf8_t*>(wqr + ko);
        bf8_t ak  = *reinterpret_cast<const bf8_t*>(wkr + ko);
        bf8_t bx0 = *reinterpret_cast<const bf8_t*>(&xlds[l31 * XS + ko]);
        bf8_t bx1 = *reinterpret_cast<const bf8_t*>(&xlds[(32 + l31) * XS + ko]);
        cq0 = MFMA32(aq, bx0, cq0);
        cq1 = MFMA32(aq, bx1, cq1);
        ck0 = MFMA32(ak, bx0, ck0);
        ck1 = MFMA32(ak, bx1, ck1);
      }
      // per-token L2 norm over d (in-register + one lane^32 exchange)
      float qs = scf[h];
      {
        float sq = 0.f, sk = 0.f;
        #pragma unroll
        for (int r = 0; r < 16; r++){ sq = fmaf(cq0[r], cq0[r], sq); sk = fmaf(ck0[r], ck0[r], sk); }
        sq += __shfl_xor(sq, 32); sk += __shfl_xor(sk, 32);
        float iq = qs * __builtin_amdgcn_rsqf(fmaxf(sq, 1e-24f));
        float ik = __builtin_amdgcn_rsqf(fmaxf(sk, 1e-24f));
        #pragma unroll
        for (int r = 0; r < 16; r++){ cq0[r] *= iq; ck0[r] *= ik; }
        cvt_tile(cq0, hi5, qf00, qf01);
        cvt_tile(ck0, hi5, kf00, kf01);
      }
      {
        float sq = 0.f, sk = 0.f;
        #pragma unroll
        for (int r = 0; r < 16; r++){ sq = fmaf(cq1[r], cq1[r], sq); sk = fmaf(ck1[r], ck1[r], sk); }
        sq += __shfl_xor(sq, 32); sk += __shfl_xor(sk, 32);
        float iq = qs * __builtin_amdgcn_rsqf(fmaxf(sq, 1e-24f));
        float ik = __builtin_amdgcn_rsqf(fmaxf(sk, 1e-24f));
        #pragma unroll
        for (int r = 0; r < 16; r++){ cq1[r] *= iq; ck1[r] *= ik; }
        cvt_tile(cq1, hi5, qf10, qf11);
        cvt_tile(ck1, hi5, kf10, kf11);
      }
    }

    // ---- phase B: v normal GEMM (A = x tokens, B = Wv rows) -> C[token][d] ----
    {
      f16_t cv0, cv1;
      float bv = vbias[32*h + l31];
      #pragma unroll
      for (int r = 0; r < 16; r++){ cv0[r] = bv; cv1[r] = bv; }
      const u16* wvr = wq + (size_t)(512 + 32*h + l31) * 256;
      #pragma unroll 4
      for (int ks = 0; ks < 16; ks++){
        const int ko = ks * 16 + 8 * l5;
        bf8_t bw  = *reinterpret_cast<const bf8_t*>(wvr + ko);
        bf8_t ax0 = *reinterpret_cast<const bf8_t*>(&xlds[l31 * XS + ko]);
        bf8_t ax1 = *reinterpret_cast<const bf8_t*>(&xlds[(32 + l31) * XS + ko]);
        cv0 = MFMA32(ax0, bw, cv0);
        cv1 = MFMA32(ax1, bw, cv1);
      }
      cvt_tile(cv0, hi5, vf0, vf1);   // keys  0..31 -> k-blocks 0,1
      cvt_tile(cv1, hi5, vf2, vf3);   // keys 32..63 -> k-blocks 2,3
    }

    // ---- phase S: S^T = K.Q^T (+bias C-init), softmax, O^T = V.P ----
    #pragma unroll
    for (int nt = 0; nt < 2; nt++){                 // query tile
      f16_t s0, s1;                                 // key tiles 0,1
      {
        const f4_t* bf0 = reinterpret_cast<const f4_t*>(biasF) + (h*4 + nt    ) * 256 + lane;
        const f4_t* bf1 = reinterpret_cast<const f4_t*>(biasF) + (h*4 + 2 + nt) * 256 + lane;
        #pragma unroll
        for (int r4 = 0; r4 < 4; r4++){
          f4_t q0 = bf0[r4 * 64], q1 = bf1[r4 * 64];
          #pragma unroll
          for (int i = 0; i < 4; i++){ s0[4*r4 + i] = q0[i]; s1[4*r4 + i] = q1[i]; }
        }
      }
      bf8_t qfa = nt ? qf10 : qf00, qfb = nt ? qf11 : qf01;
      s0 = MFMA32(kf00, qfa, s0); s0 = MFMA32(kf01, qfb, s0);
      s1 = MFMA32(kf10, qfa, s1); s1 = MFMA32(kf11, qfb, s1);
      // softmax over keys: lane pair (l, l^32) splits the keys of query l31 —
      // reduce in-register, then ONE lane^32 exchange for max and for sum.
      f16_t tm;
      #pragma unroll
      for (int r = 0; r < 16; r++) tm[r] = fmaxf(s0[r], s1[r]);
      #pragma unroll
      for (int r = 0; r < 8; r++) tm[r] = fmaxf(tm[r], tm[r+8]);
      #pragma unroll
      for (int r = 0; r < 4; r++) tm[r] = fmaxf(tm[r], tm[r+4]);
      float mx = fmaxf(fmaxf(tm[0], tm[1]), fmaxf(tm[2], tm[3]));
      mx = fmaxf(mx, __shfl_xor(mx, 32));           // other key-half, same query
      #pragma unroll
      for (int r = 0; r < 16; r++){ s0[r] = exp2f(s0[r] - mx); s1[r] = exp2f(s1[r] - mx); }
      float a0 = 0.f, a1 = 0.f, a2 = 0.f, a3 = 0.f;
      #pragma unroll
      for (int r4 = 0; r4 < 4; r4++){
        a0 += s0[4*r4 + 0] + s1[4*r4 + 0];
        a1 += s0[4*r4 + 1] + s1[4*r4 + 1];
        a2 += s0[4*r4 + 2] + s1[4*r4 + 2];
        a3 += s0[4*r4 + 3] + s1[4*r4 + 3];
      }
      float ssum = (a0 + a1) + (a2 + a3);
      ssum += __shfl_xor(ssum, 32);                 // other key-half, same query
      float invr = __builtin_amdgcn_rcpf(ssum);     // per-query (pair-consistent)
      bf8_t pf0, pf1, pf2, pf3;
      cvt_tile(s0, hi5, pf0, pf1);
      cvt_tile(s1, hi5, pf2, pf3);
      f16_t co;
      #pragma unroll
      for (int r = 0; r < 16; r++) co[r] = 0.f;
      co = MFMA32(vf0, pf0, co); co = MFMA32(vf1, pf1, co);
      co = MFMA32(vf2, pf2, co); co = MFMA32(vf3, pf3, co);
      // O^T[d][query]: lane = query; fold 1/rowsum; contiguous b64 stores
      #pragma unroll
      for (int r4 = 0; r4 < 4; r4++){
        uint2 p;
        p.x = pkbf(co[4*r4 + 0] * invr, co[4*r4 + 1] * invr);
        p.y = pkbf(co[4*r4 + 2] * invr, co[4*r4 + 3] * invr);
        *reinterpret_cast<uint2*>(&olds[(32*nt + l31) * XS + 32*h + 8*r4 + 4*l5]) = p;
      }
    }
    __syncthreads();   // olds ready; xlds dead (phases A/B done for all waves)

    // ---- proj (+ prefetch x for next window under it, T14) ----
    {
      const bool pre = (it + 1 < NWIN);
      const float* xn = x + (size_t)(b + 1) * 16384;
      float4 pf[8];
      if (pre){
        #pragma unroll
        for (int i = 0; i < 8; i++)
          pf[i] = *reinterpret_cast<const float4*>(xn + (t + 512 * i) * 4);
      }
      f16_t cp0, cp1;
      float pbv = projb[32*w + l31];
      #pragma unroll
      for (int r = 0; r < 16; r++){ cp0[r] = pbv; cp1[r] = pbv; }
      const u16* wpr = wp + (size_t)(32*w + l31) * 256;
      #pragma unroll 4
      for (int ks = 0; ks < 16; ks++){
        const int ko = ks * 16 + 8 * l5;
        bf8_t bw = *reinterpret_cast<const bf8_t*>(wpr + ko);
        bf8_t a0 = *reinterpret_cast<const bf8_t*>(&olds[l31 * XS + ko]);
        bf8_t a1 = *reinterpret_cast<const bf8_t*>(&olds[(32 + l31) * XS + ko]);
        cp0 = MFMA32(a0, bw, cp0);
        cp1 = MFMA32(a1, bw, cp1);
      }
      float* og = out + (size_t)b * 16384;
      #pragma unroll
      for (int r = 0; r < 16; r++){
        int m = (r & 3) + 8*(r >> 2) + 4*l5;
        og[m * 256 + 32*w + l31] = cp0[r];
        og[(32 + m) * 256 + 32*w + l31] = cp1[r];
      }
      if (pre){
        #pragma unroll
        for (int i = 0; i < 8; i++){
          int fi = t + 512 * i;
          uint2 p; p.x = pkbf(pf[i].x, pf[i].y); p.y = pkbf(pf[i].z, pf[i].w);
          int row = fi >> 6, c = (fi & 63) * 4;
          *reinterpret_cast<uint2*>(&xlds[row * XS + c]) = p;
        }
      }
    }
    __syncthreads();   // next window's x staged; olds consumed
  }
}

// ---------------- launch ----------------
extern "C" void kernel_launch(void* const* d_in, const int* in_sizes, int n_in,
                              void* d_out, int out_size, void* d_ws, size_t ws_size,
                              hipStream_t stream){
  const float* x     = (const float*)d_in[0];
  const float* qkvw  = (const float*)d_in[1];
  const float* qb    = (const float*)d_in[2];
  const float* vb    = (const float*)d_in[3];
  const float* scale = (const float*)d_in[4];
  const float* w1    = (const float*)d_in[5];
  const float* b1    = (const float*)d_in[6];
  const float* w2    = (const float*)d_in[7];
  const float* pw    = (const float*)d_in[8];
  const float* pb    = (const float*)d_in[9];
  const float* tab   = (const float*)d_in[10];
  const int*   idx   = (const int*)d_in[11];
  float* out = (float*)d_out;

  char* ws = (char*)d_ws;
  u16*   wqb  = (u16*)ws;                    // 393216 B : qkv_w bf16
  u16*   wpb  = (u16*)(ws + 393216);         // 131072 B : proj_w bf16
  float* bias = (float*)(ws + 524288);       // 131072 B : CPB bias in S^T C-frag order
  float* tbl  = (float*)(ws + 655360);       //   7200 B : cpb MLP out [225][8]
  float* scfp = (float*)(ws + 662560);       //     32 B : folded per-head scale

  hipLaunchKernelGGL(wconv_kernel,    dim3(256), dim3(256), 0, stream, qkvw, pw, wqb, wpb);
  hipLaunchKernelGGL(cpbmlp_kernel,   dim3(8),   dim3(256), 0, stream, tab, w1, b1, w2, tbl);
  hipLaunchKernelGGL(cpbgather_kernel,dim3(128), dim3(256), 0, stream, tbl, idx, scale, bias, scfp);
  hipLaunchKernelGGL(winattn_kernel,  dim3(512), dim3(512), 0, stream,
                     x, wqb, wpb, qb, vb, bias, scfp, pb, out);
}